// Round 10
// baseline (190.302 us; speedup 1.0000x reference)
//
#include <hip/hip_runtime.h>
#include <hip/hip_bf16.h>

#define B_  4
#define N_  2048
#define E_  256
#define H_  8
#define D_  32
#define QT  16   // q-rows per block
#define KC  64   // keys per chunk
#define HPB 4    // heads per block
#define PP  72   // P row stride (ushorts): 144B
#define IFPF 68  // infl row stride (floats): 272B
#define LOG2E 1.4426950408889634f

typedef __attribute__((ext_vector_type(8))) short bfx8;
typedef __attribute__((ext_vector_type(4))) float fx4;

__device__ __forceinline__ unsigned short f2bf(float f) {
    unsigned int u = __float_as_uint(f);
    u += 0x7fffu + ((u >> 16) & 1u);   // round-to-nearest-even
    return (unsigned short)(u >> 16);
}

// ---------- prep: Wt[n][k] = bf16(W[k][n]) for 6 weight matrices ----------
__global__ __launch_bounds__(256) void prep_w(
    const float* Wa, const float* Wb, const float* Wc,
    const float* Wd, const float* We, const float* Wf,
    unsigned short* Oa, unsigned short* Ob, unsigned short* Oc,
    unsigned short* Od, unsigned short* Oe, unsigned short* Of)
{
    int z = blockIdx.z;
    const float* src = z == 0 ? Wa : z == 1 ? Wb : z == 2 ? Wc
                     : z == 3 ? Wd : z == 4 ? We : Wf;
    unsigned short* dst = z == 0 ? Oa : z == 1 ? Ob : z == 2 ? Oc
                        : z == 3 ? Od : z == 4 ? Oe : Of;
    __shared__ float t[32][33];
    int n0 = blockIdx.x * 32, k0 = blockIdx.y * 32;
    int tx = threadIdx.x & 31, ty = threadIdx.x >> 5;
#pragma unroll
    for (int i = 0; i < 4; i++)
        t[ty + i * 8][tx] = src[(k0 + ty + i * 8) * E_ + n0 + tx];
    __syncthreads();
#pragma unroll
    for (int i = 0; i < 4; i++)
        dst[(n0 + ty + i * 8) * E_ + k0 + tx] = f2bf(t[tx][ty + i * 8]);
}

// ---------- LayerNorm: one block (256 thr) per row; bf16 out ----------
__global__ __launch_bounds__(256) void ln_kernel(const float* __restrict__ x,
                                                 const float* __restrict__ g,
                                                 const float* __restrict__ be,
                                                 unsigned short* __restrict__ out)
{
    long row = blockIdx.x;
    int t = threadIdx.x;
    float v = x[row * E_ + t];
    float s = v, s2 = v * v;
#pragma unroll
    for (int off = 32; off; off >>= 1) {
        s  += __shfl_xor(s,  off, 64);
        s2 += __shfl_xor(s2, off, 64);
    }
    __shared__ float rs[4], rs2[4];
    int w = t >> 6;
    if ((t & 63) == 0) { rs[w] = s; rs2[w] = s2; }
    __syncthreads();
    s  = rs[0] + rs[1] + rs[2] + rs[3];
    s2 = rs2[0] + rs2[1] + rs2[2] + rs2[3];
    float mu  = s * (1.0f / E_);
    float var = s2 * (1.0f / E_) - mu * mu;
    float rstd = rsqrtf(var + 1e-5f);
    out[row * E_ + t] = f2bf((v - mu) * rstd * g[t] + be[t]);
}

// ---------- bf16 MFMA GEMM core (64x64 tile, K=256 strip in LDS) ----------
// Computes C[m][n] = sum_k A[m][k] * Wt[n][k]; C stride = ldC.
__device__ __forceinline__ void gemm_core(
    const unsigned short* __restrict__ A,
    const unsigned short* __restrict__ Wt,
    const float* __restrict__ bias,
    const float* __restrict__ resid,
    void* __restrict__ Cv, int relu, int obf, int m0, int n0, int ldC)
{
    __shared__ unsigned short As[64 * 264];
    __shared__ unsigned short Bs[64 * 264];
    int tid = threadIdx.x;

    {   // stage both 64x256 strips (contiguous rows), coalesced 16B/lane
        const unsigned short* Ab = A  + (long)m0 * E_;
        const unsigned short* Bb = Wt + (long)n0 * E_;
        bfx8 va[8], vb[8];
#pragma unroll
        for (int i = 0; i < 8; i++) va[i] = *(const bfx8*)&Ab[(i * 256 + tid) * 8];
#pragma unroll
        for (int i = 0; i < 8; i++) vb[i] = *(const bfx8*)&Bb[(i * 256 + tid) * 8];
#pragma unroll
        for (int i = 0; i < 8; i++) {
            int fo = i * 256 + tid;
            int row = fo >> 5, c8 = fo & 31;
            *(bfx8*)&As[row * 264 + c8 * 8] = va[i];
            *(bfx8*)&Bs[row * 264 + c8 * 8] = vb[i];
        }
    }
    __syncthreads();

    int lane = tid & 63, w = tid >> 6;
    int c = lane & 15, g = lane >> 4;
    int wm = (w >> 1) * 32, wn = (w & 1) * 32;
    fx4 acc[2][2] = {};

#pragma unroll
    for (int ks = 0; ks < 8; ks++) {
        bfx8 a0 = *(const bfx8*)&As[(wm + c)      * 264 + ks * 32 + g * 8];
        bfx8 a1 = *(const bfx8*)&As[(wm + 16 + c) * 264 + ks * 32 + g * 8];
        bfx8 b0 = *(const bfx8*)&Bs[(wn + c)      * 264 + ks * 32 + g * 8];
        bfx8 b1 = *(const bfx8*)&Bs[(wn + 16 + c) * 264 + ks * 32 + g * 8];
        acc[0][0] = __builtin_amdgcn_mfma_f32_16x16x32_bf16(a0, b0, acc[0][0], 0, 0, 0);
        acc[0][1] = __builtin_amdgcn_mfma_f32_16x16x32_bf16(a0, b1, acc[0][1], 0, 0, 0);
        acc[1][0] = __builtin_amdgcn_mfma_f32_16x16x32_bf16(a1, b0, acc[1][0], 0, 0, 0);
        acc[1][1] = __builtin_amdgcn_mfma_f32_16x16x32_bf16(a1, b1, acc[1][1], 0, 0, 0);
    }

#pragma unroll
    for (int fm = 0; fm < 2; fm++)
#pragma unroll
        for (int r = 0; r < 4; r++) {
            int m = m0 + wm + fm * 16 + g * 4 + r;
#pragma unroll
            for (int fn = 0; fn < 2; fn++) {
                int n = n0 + wn + fn * 16 + c;
                float o = acc[fm][fn][r];
                if (bias)  o += bias[n];
                if (relu)  o = fmaxf(o, 0.f);
                if (resid) o += resid[(long)m * ldC + n];
                if (obf) ((unsigned short*)Cv)[(long)m * ldC + n] = f2bf(o);
                else     ((float*)Cv)[(long)m * ldC + n] = o;
            }
        }
}

__global__ __launch_bounds__(256, 2) void gemm_mfma(
    const unsigned short* __restrict__ A,
    const unsigned short* __restrict__ Wt,
    const float* __restrict__ bias,
    const float* __restrict__ resid,
    void* __restrict__ Cv, int relu, int obf)
{
    gemm_core(A, Wt, bias, resid, Cv, relu, obf,
              blockIdx.x * 64, blockIdx.y * 64, E_);
}

// merged QKV. z==2 computes V^T DIRECTLY: Vt[ch][tok] = sum_k Wvt[ch][k]*X[tok][k]
// (roles of A/W swapped; output channel-major with ldC = 8192).
__global__ __launch_bounds__(256, 2) void gemm_qkv(
    const unsigned short* __restrict__ A,
    const unsigned short* __restrict__ Wq, unsigned short* __restrict__ qo,
    const unsigned short* __restrict__ Wk, unsigned short* __restrict__ ko,
    const unsigned short* __restrict__ Wv, unsigned short* __restrict__ vto)
{
    int z = blockIdx.z;
    if (z == 2) {
        gemm_core(Wv, A, nullptr, nullptr, vto, 0, 1,
                  blockIdx.y * 64, blockIdx.x * 64, B_ * N_);
    } else {
        const unsigned short* Wt = z == 0 ? Wq : Wk;
        unsigned short*       Cv = z == 0 ? qo : ko;
        gemm_core(A, Wt, nullptr, nullptr, Cv, 0, 1,
                  blockIdx.x * 64, blockIdx.y * 64, E_);
    }
}

// ---------- MFMA flash attention: QT=16, 4 heads/block, 4 blocks/CU ----------
// fixed-max softmax: p' = exp2(s*log2e - M2); out = (sum p'*rw*v)/(sum p').
// V^T pre-transposed in global [256][8192] -> PV B-fragments load directly
// (no V LDS, no pack). infl f32 double-buffer, 1 barrier/body.
__global__ __launch_bounds__(256, 4) void attn_mfma(
    const unsigned short* __restrict__ q,
    const unsigned short* __restrict__ k,
    const unsigned short* __restrict__ vt,   // [E_][B_*N_] channel-major
    const float* __restrict__ infl,
    const float* __restrict__ iw1p, const float* __restrict__ ib1p,
    const float* __restrict__ iw2p, const float* __restrict__ ib2p,
    unsigned short* __restrict__ out)
{
    const int bx  = blockIdx.x;                 // 1024 blocks
    const int xcd = bx & 7;
    const int b   = xcd >> 1;                   // batch
    const int hg  = (xcd & 1) * HPB;            // head-group base
    const int q0  = (bx >> 3) * QT;
    const int tid = threadIdx.x;
    const int h    = tid >> 6;                  // wave id 0..3
    const int head = hg + h;
    const int lane = tid & 63;
    const int c = lane & 15, g = lane >> 4, g4 = g * 4;

    const float iw1e = iw1p[0] * LOG2E, ib1e = ib1p[0] * LOG2E;
    const float iw2 = iw2p[0], ib2 = ib2p[0];
    const float scale2 = 0.17677669529663687f * LOG2E;  // log2e/sqrt(32)
    const float cadd = ib1e - 16.0f * LOG2E;            // ib1*log2e - M2

    __shared__ unsigned short p_lds[HPB][QT][PP];   // 9216B wave-private
    __shared__ float infl_lds[2][QT][IFPF];         // 8704B block-shared dbuf

    // Q fragment
    bfx8 qf = *(const bfx8*)&q[((long)(b * N_ + q0 + c)) * E_ + head * D_ + g * 8];

    const unsigned short* kbase = &k[((long)(b * N_) + c) * E_ + head * D_ + g * 8];
    const long MT = (long)B_ * N_;   // 8192
    const unsigned short* vt0 = &vt[((long)(head * D_ + c)) * MT + b * N_ + g * 8];
    const unsigned short* vt1 = vt0 + 16 * MT;

    // cooperative infl staging: 256 thr = 16 rows x 16 thr; 1 float4 each
    const int irow = tid >> 4, icol = (tid & 15) * 4;
    const float* ibase = &infl[((long)(b * N_ + q0 + irow)) * N_ + icol];

    fx4 o0 = {0,0,0,0}, o1 = {0,0,0,0};
    float l_acc = 0.f;
    const fx4 zero = {0,0,0,0};
    fx4 st0, st1, st2, st3;

    // ---------------- prologue: chunk 0 ----------------
    *(float4*)&infl_lds[0][irow][icol] = *(const float4*)&ibase[0];
    float4 fA = *(const float4*)&ibase[KC];          // infl(1)
    bfx8 ck0 = *(const bfx8*)(kbase +  0L * E_);
    bfx8 ck1 = *(const bfx8*)(kbase + 16L * E_);
    bfx8 ck2 = *(const bfx8*)(kbase + 32L * E_);
    bfx8 ck3 = *(const bfx8*)(kbase + 48L * E_);
    bfx8 cv00 = *(const bfx8*)&vt0[0];
    bfx8 cv01 = *(const bfx8*)&vt0[32];
    bfx8 cv10 = *(const bfx8*)&vt1[0];
    bfx8 cv11 = *(const bfx8*)&vt1[32];
    __syncthreads();
    __builtin_amdgcn_s_setprio(1);
    st0 = __builtin_amdgcn_mfma_f32_16x16x32_bf16(ck0, qf, zero, 0, 0, 0);
    st1 = __builtin_amdgcn_mfma_f32_16x16x32_bf16(ck1, qf, zero, 0, 0, 0);
    st2 = __builtin_amdgcn_mfma_f32_16x16x32_bf16(ck2, qf, zero, 0, 0, 0);
    st3 = __builtin_amdgcn_mfma_f32_16x16x32_bf16(ck3, qf, zero, 0, 0, 0);
    __builtin_amdgcn_s_setprio(0);

    // ---------------- main loop ----------------
    for (int kk = 0; kk < N_; kk += KC) {
        const int cur = (kk >> 6) & 1, nxt = cur ^ 1;
        const int kn  = (kk +     KC) & (N_ - 1);
        const int kn2 = (kk + 2 * KC) & (N_ - 1);

        // prefetch next chunk: K first (consumed this body's bottom),
        // then V^T (consumed NEXT body's PV), then infl 2 ahead
        bfx8 nk0 = *(const bfx8*)(kbase + (long)(kn +  0) * E_);
        bfx8 nk1 = *(const bfx8*)(kbase + (long)(kn + 16) * E_);
        bfx8 nk2 = *(const bfx8*)(kbase + (long)(kn + 32) * E_);
        bfx8 nk3 = *(const bfx8*)(kbase + (long)(kn + 48) * E_);
        bfx8 nv00 = *(const bfx8*)&vt0[kn];
        bfx8 nv01 = *(const bfx8*)&vt0[kn + 32];
        bfx8 nv10 = *(const bfx8*)&vt1[kn];
        bfx8 nv11 = *(const bfx8*)&vt1[kn + 32];
        float4 fN = *(const float4*)&ibase[kn2];

        // write infl(kk+1) into buf[nxt] from regs loaded last body (no wait)
        *(float4*)&infl_lds[nxt][irow][icol] = fA;

        // softmax(kk): st + infl_lds[cur] -> pr -> p_lds
#pragma unroll
        for (int t = 0; t < 4; t++) {
            float4 fr4 = *(const float4*)&infl_lds[cur][c][t * 16 + g4];
            float fr[4] = {fr4.x, fr4.y, fr4.z, fr4.w};
            fx4 stv = (t == 0) ? st0 : (t == 1) ? st1 : (t == 2) ? st2 : st3;
            float pr[4];
#pragma unroll
            for (int r = 0; r < 4; r++) {
                float s = fmaf(stv[r], scale2, fmaf(fr[r], iw1e, cadd));
                float p = __builtin_amdgcn_exp2f(s);
                l_acc += p;
                pr[r] = p * fmaf(iw2, fr[r], ib2);
            }
            unsigned int lo = (unsigned int)f2bf(pr[0]) | ((unsigned int)f2bf(pr[1]) << 16);
            unsigned int hi = (unsigned int)f2bf(pr[2]) | ((unsigned int)f2bf(pr[3]) << 16);
            *(uint2*)&p_lds[h][c][t * 16 + g4] = make_uint2(lo, hi);
        }

        // PV(kk): p_lds + prefetched V^T regs (loaded one body ago)
        __builtin_amdgcn_s_setprio(1);
        {
            bfx8 pf0 = *(const bfx8*)&p_lds[h][c][g * 8];
            bfx8 pf1 = *(const bfx8*)&p_lds[h][c][g * 8 + 32];
            o0 = __builtin_amdgcn_mfma_f32_16x16x32_bf16(pf0, cv00, o0, 0, 0, 0);
            o0 = __builtin_amdgcn_mfma_f32_16x16x32_bf16(pf1, cv01, o0, 0, 0, 0);
            o1 = __builtin_amdgcn_mfma_f32_16x16x32_bf16(pf0, cv10, o1, 0, 0, 0);
            o1 = __builtin_amdgcn_mfma_f32_16x16x32_bf16(pf1, cv11, o1, 0, 0, 0);
        }
        __builtin_amdgcn_s_setprio(0);

        __syncthreads();   // buf[cur] reads done; buf[nxt] visible

        if (kk != N_ - KC) {
            // QK(kk+1): K issued this body's top (~400cyc ago, L2-hot)
            __builtin_amdgcn_s_setprio(1);
            st0 = __builtin_amdgcn_mfma_f32_16x16x32_bf16(nk0, qf, zero, 0, 0, 0);
            st1 = __builtin_amdgcn_mfma_f32_16x16x32_bf16(nk1, qf, zero, 0, 0, 0);
            st2 = __builtin_amdgcn_mfma_f32_16x16x32_bf16(nk2, qf, zero, 0, 0, 0);
            st3 = __builtin_amdgcn_mfma_f32_16x16x32_bf16(nk3, qf, zero, 0, 0, 0);
            __builtin_amdgcn_s_setprio(0);
        }
        cv00 = nv00; cv01 = nv01; cv10 = nv10; cv11 = nv11;
        fA = fN;
    }

    // ---------------- epilogue ----------------
    float l_red = l_acc;
    l_red += __shfl_xor(l_red, 16);
    l_red += __shfl_xor(l_red, 32);
#pragma unroll
    for (int r = 0; r < 4; r++) {
        float l_q = __shfl(l_red, (lane & 48) | (g4 + r), 64);
        float inv = 1.0f / l_q;
        long row = ((long)(b * N_ + q0 + g4 + r)) * E_ + head * D_;
        out[row + c]      = f2bf(o0[r] * inv);
        out[row + 16 + c] = f2bf(o1[r] * inv);
    }
}

// ------------------------------- launch ---------------------------------------
extern "C" void kernel_launch(void* const* d_in, const int* in_sizes, int n_in,
                              void* d_out, int out_size, void* d_ws, size_t ws_size,
                              hipStream_t stream)
{
    (void)in_sizes; (void)n_in; (void)out_size; (void)ws_size;
    const float* x    = (const float*)d_in[0];
    const float* infl = (const float*)d_in[1];
    const float* Wq   = (const float*)d_in[2];
    const float* Wk   = (const float*)d_in[3];
    const float* Wv   = (const float*)d_in[4];
    const float* Wo   = (const float*)d_in[5];
    const float* bo   = (const float*)d_in[6];
    const float* iw1  = (const float*)d_in[7];
    const float* ib1  = (const float*)d_in[8];
    const float* iw2  = (const float*)d_in[9];
    const float* ib2  = (const float*)d_in[10];
    const float* W1   = (const float*)d_in[11];
    const float* b1   = (const float*)d_in[12];
    const float* W2   = (const float*)d_in[13];
    const float* b2   = (const float*)d_in[14];
    const float* g1   = (const float*)d_in[15];
    const float* be1  = (const float*)d_in[16];
    const float* g2   = (const float*)d_in[17];
    const float* be2  = (const float*)d_in[18];

    char* base = (char*)d_ws;
    float*          hb  = (float*)base;                                   // 8 MB
    unsigned short* lnb = (unsigned short*)(base + (8  << 20));           // 4 MB
    unsigned short* qb  = (unsigned short*)(base + (12 << 20));           // 4 MB
    unsigned short* kb  = (unsigned short*)(base + (16 << 20));           // 4 MB
    unsigned short* vtb = (unsigned short*)(base + (20 << 20));           // 4 MB (V^T)
    unsigned short* wqt = (unsigned short*)(base + (24 << 20));           // 6x128KB
    unsigned short* wkt = wqt + 65536;
    unsigned short* wvt = wkt + 65536;
    unsigned short* wot = wvt + 65536;
    unsigned short* w1t = wot + 65536;
    unsigned short* w2t = w1t + 65536;

    dim3 gemm_grid(128, 4);

    prep_w<<<dim3(8, 8, 6), 256, 0, stream>>>(Wq, Wk, Wv, Wo, W1, W2,
                                              wqt, wkt, wvt, wot, w1t, w2t);
    // 1. ln1 = LN(x) -> bf16
    ln_kernel<<<B_ * N_, 256, 0, stream>>>(x, g1, be1, lnb);
    // 2. q, k, V^T in ONE launch (z==2 writes transposed V directly)
    gemm_qkv<<<dim3(128, 4, 3), 256, 0, stream>>>(lnb, wqt, qb, wkt, kb, wvt, vtb);
    // 3. attention (bf16 out into lnb); 1024 blocks, 4/CU
    attn_mfma<<<B_ * (N_ / QT) * 2, 256, 0, stream>>>(qb, kb, vtb, infl,
                                                      iw1, ib1, iw2, ib2, lnb);
    // 4. h = attn @ Wo + bo + x (fp32)
    gemm_mfma<<<gemm_grid, 256, 0, stream>>>(lnb, wot, bo, x, hb, 0, 0);
    // 5. ln2 = LN(h) -> bf16
    ln_kernel<<<B_ * N_, 256, 0, stream>>>(hb, g2, be2, lnb);
    // 6. t = relu(ln2 @ W1 + b1) -> bf16 (reuse qb)
    gemm_mfma<<<gemm_grid, 256, 0, stream>>>(lnb, w1t, b1, nullptr, qb, 1, 1);
    // 7. out = t @ W2 + b2 + h (fp32)
    gemm_mfma<<<gemm_grid, 256, 0, stream>>>(qb, w2t, b2, hb, (float*)d_out, 0, 0);
}

// Round 11
// 137.050 us; speedup vs baseline: 1.3886x; 1.3886x over previous
//
#include <hip/hip_runtime.h>
#include <hip/hip_bf16.h>

#define B_  4
#define N_  2048
#define E_  256
#define H_  8
#define D_  32
#define QT  32   // q-rows per block
#define KC  64   // keys per chunk
#define HPB 4    // heads per block
#define VTP 72   // V^T row stride (ushorts): 144B
#define PP  72   // P row stride (ushorts)
#define IFPF 68  // infl row stride (floats): 272B
#define LOG2E 1.4426950408889634f

typedef __attribute__((ext_vector_type(8))) short bfx8;
typedef __attribute__((ext_vector_type(4))) float fx4;

__device__ __forceinline__ unsigned short f2bf(float f) {
    unsigned int u = __float_as_uint(f);
    u += 0x7fffu + ((u >> 16) & 1u);   // round-to-nearest-even
    return (unsigned short)(u >> 16);
}

// ---------- prep: Wt[n][k] = bf16(W[k][n]) for 6 weight matrices ----------
__global__ __launch_bounds__(256) void prep_w(
    const float* Wa, const float* Wb, const float* Wc,
    const float* Wd, const float* We, const float* Wf,
    unsigned short* Oa, unsigned short* Ob, unsigned short* Oc,
    unsigned short* Od, unsigned short* Oe, unsigned short* Of)
{
    int z = blockIdx.z;
    const float* src = z == 0 ? Wa : z == 1 ? Wb : z == 2 ? Wc
                     : z == 3 ? Wd : z == 4 ? We : Wf;
    unsigned short* dst = z == 0 ? Oa : z == 1 ? Ob : z == 2 ? Oc
                        : z == 3 ? Od : z == 4 ? Oe : Of;
    __shared__ float t[32][33];
    int n0 = blockIdx.x * 32, k0 = blockIdx.y * 32;
    int tx = threadIdx.x & 31, ty = threadIdx.x >> 5;
#pragma unroll
    for (int i = 0; i < 4; i++)
        t[ty + i * 8][tx] = src[(k0 + ty + i * 8) * E_ + n0 + tx];
    __syncthreads();
#pragma unroll
    for (int i = 0; i < 4; i++)
        dst[(n0 + ty + i * 8) * E_ + k0 + tx] = f2bf(t[tx][ty + i * 8]);
}

// ---------- LayerNorm: one block (256 thr) per row; bf16 out ----------
__global__ __launch_bounds__(256) void ln_kernel(const float* __restrict__ x,
                                                 const float* __restrict__ g,
                                                 const float* __restrict__ be,
                                                 unsigned short* __restrict__ out)
{
    long row = blockIdx.x;
    int t = threadIdx.x;
    float v = x[row * E_ + t];
    float s = v, s2 = v * v;
#pragma unroll
    for (int off = 32; off; off >>= 1) {
        s  += __shfl_xor(s,  off, 64);
        s2 += __shfl_xor(s2, off, 64);
    }
    __shared__ float rs[4], rs2[4];
    int w = t >> 6;
    if ((t & 63) == 0) { rs[w] = s; rs2[w] = s2; }
    __syncthreads();
    s  = rs[0] + rs[1] + rs[2] + rs[3];
    s2 = rs2[0] + rs2[1] + rs2[2] + rs2[3];
    float mu  = s * (1.0f / E_);
    float var = s2 * (1.0f / E_) - mu * mu;
    float rstd = rsqrtf(var + 1e-5f);
    out[row * E_ + t] = f2bf((v - mu) * rstd * g[t] + be[t]);
}

// ---------- bf16 MFMA GEMM core (64x64 tile, K=256 strip in LDS) ----------
// C[m][n] = sum_k A[m][k] * Wt[n][k]; C stride = ldC.
__device__ __forceinline__ void gemm_core(
    const unsigned short* __restrict__ A,
    const unsigned short* __restrict__ Wt,
    const float* __restrict__ bias,
    const float* __restrict__ resid,
    void* __restrict__ Cv, int relu, int obf, int m0, int n0, int ldC)
{
    __shared__ unsigned short As[64 * 264];
    __shared__ unsigned short Bs[64 * 264];
    int tid = threadIdx.x;

    {   // stage both 64x256 strips (contiguous rows), coalesced 16B/lane
        const unsigned short* Ab = A  + (long)m0 * E_;
        const unsigned short* Bb = Wt + (long)n0 * E_;
        bfx8 va[8], vb[8];
#pragma unroll
        for (int i = 0; i < 8; i++) va[i] = *(const bfx8*)&Ab[(i * 256 + tid) * 8];
#pragma unroll
        for (int i = 0; i < 8; i++) vb[i] = *(const bfx8*)&Bb[(i * 256 + tid) * 8];
#pragma unroll
        for (int i = 0; i < 8; i++) {
            int fo = i * 256 + tid;
            int row = fo >> 5, c8 = fo & 31;
            *(bfx8*)&As[row * 264 + c8 * 8] = va[i];
            *(bfx8*)&Bs[row * 264 + c8 * 8] = vb[i];
        }
    }
    __syncthreads();

    int lane = tid & 63, w = tid >> 6;
    int c = lane & 15, g = lane >> 4;
    int wm = (w >> 1) * 32, wn = (w & 1) * 32;
    fx4 acc[2][2] = {};

#pragma unroll
    for (int ks = 0; ks < 8; ks++) {
        bfx8 a0 = *(const bfx8*)&As[(wm + c)      * 264 + ks * 32 + g * 8];
        bfx8 a1 = *(const bfx8*)&As[(wm + 16 + c) * 264 + ks * 32 + g * 8];
        bfx8 b0 = *(const bfx8*)&Bs[(wn + c)      * 264 + ks * 32 + g * 8];
        bfx8 b1 = *(const bfx8*)&Bs[(wn + 16 + c) * 264 + ks * 32 + g * 8];
        acc[0][0] = __builtin_amdgcn_mfma_f32_16x16x32_bf16(a0, b0, acc[0][0], 0, 0, 0);
        acc[0][1] = __builtin_amdgcn_mfma_f32_16x16x32_bf16(a0, b1, acc[0][1], 0, 0, 0);
        acc[1][0] = __builtin_amdgcn_mfma_f32_16x16x32_bf16(a1, b0, acc[1][0], 0, 0, 0);
        acc[1][1] = __builtin_amdgcn_mfma_f32_16x16x32_bf16(a1, b1, acc[1][1], 0, 0, 0);
    }

#pragma unroll
    for (int fm = 0; fm < 2; fm++)
#pragma unroll
        for (int r = 0; r < 4; r++) {
            int m = m0 + wm + fm * 16 + g * 4 + r;
#pragma unroll
            for (int fn = 0; fn < 2; fn++) {
                int n = n0 + wn + fn * 16 + c;
                float o = acc[fm][fn][r];
                if (bias)  o += bias[n];
                if (relu)  o = fmaxf(o, 0.f);
                if (resid) o += resid[(long)m * ldC + n];
                if (obf) ((unsigned short*)Cv)[(long)m * ldC + n] = f2bf(o);
                else     ((float*)Cv)[(long)m * ldC + n] = o;
            }
        }
}

__global__ __launch_bounds__(256, 2) void gemm_mfma(
    const unsigned short* __restrict__ A,
    const unsigned short* __restrict__ Wt,
    const float* __restrict__ bias,
    const float* __restrict__ resid,
    void* __restrict__ Cv, int relu, int obf)
{
    gemm_core(A, Wt, bias, resid, Cv, relu, obf,
              blockIdx.x * 64, blockIdx.y * 64, E_);
}

// merged QKV. z==2 computes V^T: Vt[ch][tok] = sum_k Wvt[ch][k]*X[tok][k]
// (roles of A/W swapped; channel-major output, ldC = 8192).
__global__ __launch_bounds__(256, 2) void gemm_qkv(
    const unsigned short* __restrict__ A,
    const unsigned short* __restrict__ Wq, unsigned short* __restrict__ qo,
    const unsigned short* __restrict__ Wk, unsigned short* __restrict__ ko,
    const unsigned short* __restrict__ Wv, unsigned short* __restrict__ vto)
{
    int z = blockIdx.z;
    if (z == 2) {
        gemm_core(Wv, A, nullptr, nullptr, vto, 0, 1,
                  blockIdx.y * 64, blockIdx.x * 64, B_ * N_);
    } else {
        const unsigned short* Wt = z == 0 ? Wq : Wk;
        unsigned short*       Cv = z == 0 ? qo : Wk ? ko : ko;
        Cv = z == 0 ? qo : ko;
        gemm_core(A, Wt, nullptr, nullptr, Cv, 0, 1,
                  blockIdx.x * 64, blockIdx.y * 64, E_);
    }
}

// ---------- MFMA flash attention: QT=32, 4 heads/block, dbuf infl ------------
// R9 structure (95us) + V^T pre-transposed in global: staging is a coalesced
// wave-private copy (8x128B segments -> b128 ds_write, conflict-free), no pack
// VALU. infl staged as f32 (no bf16 pack/unpack). 1 barrier/body.
__global__ __launch_bounds__(256, 2) void attn_mfma(
    const unsigned short* __restrict__ q,
    const unsigned short* __restrict__ k,
    const unsigned short* __restrict__ vt,   // [E_][B_*N_] channel-major
    const float* __restrict__ infl,
    const float* __restrict__ iw1p, const float* __restrict__ ib1p,
    const float* __restrict__ iw2p, const float* __restrict__ ib2p,
    unsigned short* __restrict__ out)
{
    const int bx  = blockIdx.x;                 // 512 blocks
    const int xcd = bx & 7;
    const int b   = xcd >> 1;                   // batch
    const int hg  = (xcd & 1) * HPB;            // head-group base
    const int q0  = (bx >> 3) * QT;
    const int tid = threadIdx.x;
    const int h    = tid >> 6;                  // wave id 0..3
    const int head = hg + h;
    const int lane = tid & 63;
    const int c = lane & 15, g = lane >> 4, g4 = g * 4;

    const float iw1e = iw1p[0] * LOG2E, ib1e = ib1p[0] * LOG2E;
    const float iw2 = iw2p[0], ib2 = ib2p[0];
    const float scale2 = 0.17677669529663687f * LOG2E;  // log2e/sqrt(32)
    const float cadd = ib1e - 16.0f * LOG2E;            // ib1*log2e - M2

    __shared__ unsigned short vt_lds[HPB][D_][VTP];     // 18432B wave-private
    __shared__ unsigned short p_lds[HPB][QT][PP];       // 18432B wave-private
    __shared__ float infl_lds[2][QT][IFPF];             // 17408B block dbuf

    // Q fragments (2 q-subtiles)
    bfx8 qf0 = *(const bfx8*)&q[((long)(b * N_ + q0 +      c)) * E_ + head * D_ + g * 8];
    bfx8 qf1 = *(const bfx8*)&q[((long)(b * N_ + q0 + 16 + c)) * E_ + head * D_ + g * 8];

    const unsigned short* kbase = &k[((long)(b * N_) + c) * E_ + head * D_ + g * 8];
    // V^T staging coords: row = (lane>>3)+8i (d-channel), keys = (lane&7)*8
    const long MT = (long)B_ * N_;   // 8192
    const int vrow = lane >> 3, vcol = (lane & 7) * 8;
    const unsigned short* vtg = &vt[((long)(head * D_ + vrow)) * MT + b * N_ + vcol];

    // cooperative infl staging: 256 thr = 32 rows x 8 thr; 2 float4 each
    const int irow = tid >> 3, icol = (tid & 7) * 8;
    const float* ibase = &infl[((long)(b * N_ + q0 + irow)) * N_ + icol];

    fx4 o00 = {0,0,0,0}, o01 = {0,0,0,0}, o10 = {0,0,0,0}, o11 = {0,0,0,0};
    float l0 = 0.f, l1 = 0.f;
    const fx4 zero = {0,0,0,0};
    fx4 st[2][4];   // [qs][kt], compile-time indices only

    // ---------------- prologue: chunk 0 ----------------
    float4 i00 = *(const float4*)&ibase[0];
    float4 i01 = *(const float4*)&ibase[4];
    float4 fA0 = *(const float4*)&ibase[KC];
    float4 fA1 = *(const float4*)&ibase[KC + 4];
    bfx8 nk0 = *(const bfx8*)(kbase +  0L * E_);
    bfx8 nk1 = *(const bfx8*)(kbase + 16L * E_);
    bfx8 nk2 = *(const bfx8*)(kbase + 32L * E_);
    bfx8 nk3 = *(const bfx8*)(kbase + 48L * E_);
    bfx8 nv0 = *(const bfx8*)(vtg +  0L * MT);
    bfx8 nv1 = *(const bfx8*)(vtg +  8L * MT);
    bfx8 nv2 = *(const bfx8*)(vtg + 16L * MT);
    bfx8 nv3 = *(const bfx8*)(vtg + 24L * MT);
    {   // infl(0) -> buf0 (f32, no pack)
        *(float4*)&infl_lds[0][irow][icol]     = i00;
        *(float4*)&infl_lds[0][irow][icol + 4] = i01;
    }
    __syncthreads();
    // QK(0)
    __builtin_amdgcn_s_setprio(1);
    st[0][0] = __builtin_amdgcn_mfma_f32_16x16x32_bf16(nk0, qf0, zero, 0, 0, 0);
    st[1][0] = __builtin_amdgcn_mfma_f32_16x16x32_bf16(nk0, qf1, zero, 0, 0, 0);
    st[0][1] = __builtin_amdgcn_mfma_f32_16x16x32_bf16(nk1, qf0, zero, 0, 0, 0);
    st[1][1] = __builtin_amdgcn_mfma_f32_16x16x32_bf16(nk1, qf1, zero, 0, 0, 0);
    st[0][2] = __builtin_amdgcn_mfma_f32_16x16x32_bf16(nk2, qf0, zero, 0, 0, 0);
    st[1][2] = __builtin_amdgcn_mfma_f32_16x16x32_bf16(nk2, qf1, zero, 0, 0, 0);
    st[0][3] = __builtin_amdgcn_mfma_f32_16x16x32_bf16(nk3, qf0, zero, 0, 0, 0);
    st[1][3] = __builtin_amdgcn_mfma_f32_16x16x32_bf16(nk3, qf1, zero, 0, 0, 0);
    __builtin_amdgcn_s_setprio(0);
    {   // V-stage(0): straight b128 copies, no VALU
        *(bfx8*)&vt_lds[h][vrow     ][vcol] = nv0;
        *(bfx8*)&vt_lds[h][vrow +  8][vcol] = nv1;
        *(bfx8*)&vt_lds[h][vrow + 16][vcol] = nv2;
        *(bfx8*)&vt_lds[h][vrow + 24][vcol] = nv3;
    }

    // ---------------- main loop ----------------
    for (int kk = 0; kk < N_; kk += KC) {
        const int cur = (kk >> 6) & 1, nxt = cur ^ 1;
        const int kn  = (kk +     KC) & (N_ - 1);
        const int kn2 = (kk + 2 * KC) & (N_ - 1);

        // issue next-chunk loads (V^T, K; infl 2 ahead)
        nv0 = *(const bfx8*)(vtg +  0L * MT + kn);
        nv1 = *(const bfx8*)(vtg +  8L * MT + kn);
        nv2 = *(const bfx8*)(vtg + 16L * MT + kn);
        nv3 = *(const bfx8*)(vtg + 24L * MT + kn);
        nk0 = *(const bfx8*)(kbase + (long)(kn +  0) * E_);
        nk1 = *(const bfx8*)(kbase + (long)(kn + 16) * E_);
        nk2 = *(const bfx8*)(kbase + (long)(kn + 32) * E_);
        nk3 = *(const bfx8*)(kbase + (long)(kn + 48) * E_);
        float4 fN0 = *(const float4*)&ibase[kn2];
        float4 fN1 = *(const float4*)&ibase[kn2 + 4];

        // write infl(kk+1) into buf[nxt] from regs loaded LAST body (no wait)
        *(float4*)&infl_lds[nxt][irow][icol]     = fA0;
        *(float4*)&infl_lds[nxt][irow][icol + 4] = fA1;

        // softmax(kk): st + infl_lds[cur] -> pr -> p_lds
#pragma unroll
        for (int qs = 0; qs < 2; qs++) {
#pragma unroll
            for (int t = 0; t < 4; t++) {
                float4 fr4 = *(const float4*)&infl_lds[cur][qs * 16 + c][t * 16 + g4];
                float fr[4] = {fr4.x, fr4.y, fr4.z, fr4.w};
                float pr[4];
#pragma unroll
                for (int r = 0; r < 4; r++) {
                    float s = fmaf(st[qs][t][r], scale2, fmaf(fr[r], iw1e, cadd));
                    float p = __builtin_amdgcn_exp2f(s);
                    if (qs == 0) l0 += p; else l1 += p;
                    pr[r] = p * fmaf(iw2, fr[r], ib2);
                }
                unsigned int lo = (unsigned int)f2bf(pr[0]) | ((unsigned int)f2bf(pr[1]) << 16);
                unsigned int hi = (unsigned int)f2bf(pr[2]) | ((unsigned int)f2bf(pr[3]) << 16);
                *(uint2*)&p_lds[h][qs * 16 + c][t * 16 + g4] = make_uint2(lo, hi);
            }
        }

        // PV(kk)
        __builtin_amdgcn_s_setprio(1);
#pragma unroll
        for (int kh = 0; kh < 2; kh++) {
            bfx8 vf0 = *(const bfx8*)&vt_lds[h][c][g * 8 + kh * 32];
            bfx8 vf1 = *(const bfx8*)&vt_lds[h][16 + c][g * 8 + kh * 32];
            bfx8 pf0 = *(const bfx8*)&p_lds[h][c][g * 8 + kh * 32];
            bfx8 pf1 = *(const bfx8*)&p_lds[h][16 + c][g * 8 + kh * 32];
            o00 = __builtin_amdgcn_mfma_f32_16x16x32_bf16(pf0, vf0, o00, 0, 0, 0);
            o01 = __builtin_amdgcn_mfma_f32_16x16x32_bf16(pf0, vf1, o01, 0, 0, 0);
            o10 = __builtin_amdgcn_mfma_f32_16x16x32_bf16(pf1, vf0, o10, 0, 0, 0);
            o11 = __builtin_amdgcn_mfma_f32_16x16x32_bf16(pf1, vf1, o11, 0, 0, 0);
        }
        __builtin_amdgcn_s_setprio(0);

        __syncthreads();   // buf[cur] reads done; buf[nxt] writes visible

        if (kk != N_ - KC) {
            // QK(kk+1): K issued one body ago
            __builtin_amdgcn_s_setprio(1);
            st[0][0] = __builtin_amdgcn_mfma_f32_16x16x32_bf16(nk0, qf0, zero, 0, 0, 0);
            st[1][0] = __builtin_amdgcn_mfma_f32_16x16x32_bf16(nk0, qf1, zero, 0, 0, 0);
            st[0][1] = __builtin_amdgcn_mfma_f32_16x16x32_bf16(nk1, qf0, zero, 0, 0, 0);
            st[1][1] = __builtin_amdgcn_mfma_f32_16x16x32_bf16(nk1, qf1, zero, 0, 0, 0);
            st[0][2] = __builtin_amdgcn_mfma_f32_16x16x32_bf16(nk2, qf0, zero, 0, 0, 0);
            st[1][2] = __builtin_amdgcn_mfma_f32_16x16x32_bf16(nk2, qf1, zero, 0, 0, 0);
            st[0][3] = __builtin_amdgcn_mfma_f32_16x16x32_bf16(nk3, qf0, zero, 0, 0, 0);
            st[1][3] = __builtin_amdgcn_mfma_f32_16x16x32_bf16(nk3, qf1, zero, 0, 0, 0);
            __builtin_amdgcn_s_setprio(0);
            // V-stage(kk+1): b128 copies
            *(bfx8*)&vt_lds[h][vrow     ][vcol] = nv0;
            *(bfx8*)&vt_lds[h][vrow +  8][vcol] = nv1;
            *(bfx8*)&vt_lds[h][vrow + 16][vcol] = nv2;
            *(bfx8*)&vt_lds[h][vrow + 24][vcol] = nv3;
        }
        fA0 = fN0; fA1 = fN1;
    }

    // ---------------- epilogue ----------------
    float l0r = l0;
    l0r += __shfl_xor(l0r, 16); l0r += __shfl_xor(l0r, 32);
    float l1r = l1;
    l1r += __shfl_xor(l1r, 16); l1r += __shfl_xor(l1r, 32);
#pragma unroll
    for (int r = 0; r < 4; r++) {
        int src = (lane & 48) | (g4 + r);
        float inv0 = 1.0f / __shfl(l0r, src, 64);
        float inv1 = 1.0f / __shfl(l1r, src, 64);
        long row0 = ((long)(b * N_ + q0 +      g4 + r)) * E_ + head * D_;
        long row1 = ((long)(b * N_ + q0 + 16 + g4 + r)) * E_ + head * D_;
        out[row0 + c]      = f2bf(o00[r] * inv0);
        out[row0 + 16 + c] = f2bf(o01[r] * inv0);
        out[row1 + c]      = f2bf(o10[r] * inv1);
        out[row1 + 16 + c] = f2bf(o11[r] * inv1);
    }
}

// ------------------------------- launch ---------------------------------------
extern "C" void kernel_launch(void* const* d_in, const int* in_sizes, int n_in,
                              void* d_out, int out_size, void* d_ws, size_t ws_size,
                              hipStream_t stream)
{
    (void)in_sizes; (void)n_in; (void)out_size; (void)ws_size;
    const float* x    = (const float*)d_in[0];
    const float* infl = (const float*)d_in[1];
    const float* Wq   = (const float*)d_in[2];
    const float* Wk   = (const float*)d_in[3];
    const float* Wv   = (const float*)d_in[4];
    const float* Wo   = (const float*)d_in[5];
    const float* bo   = (const float*)d_in[6];
    const float* iw1  = (const float*)d_in[7];
    const float* ib1  = (const float*)d_in[8];
    const float* iw2  = (const float*)d_in[9];
    const float* ib2  = (const float*)d_in[10];
    const float* W1   = (const float*)d_in[11];
    const float* b1   = (const float*)d_in[12];
    const float* W2   = (const float*)d_in[13];
    const float* b2   = (const float*)d_in[14];
    const float* g1   = (const float*)d_in[15];
    const float* be1  = (const float*)d_in[16];
    const float* g2   = (const float*)d_in[17];
    const float* be2  = (const float*)d_in[18];

    char* base = (char*)d_ws;
    float*          hb  = (float*)base;                                   // 8 MB
    unsigned short* lnb = (unsigned short*)(base + (8  << 20));           // 4 MB
    unsigned short* qb  = (unsigned short*)(base + (12 << 20));           // 4 MB
    unsigned short* kb  = (unsigned short*)(base + (16 << 20));           // 4 MB
    unsigned short* vtb = (unsigned short*)(base + (20 << 20));           // 4 MB (V^T)
    unsigned short* wqt = (unsigned short*)(base + (24 << 20));           // 6x128KB
    unsigned short* wkt = wqt + 65536;
    unsigned short* wvt = wkt + 65536;
    unsigned short* wot = wvt + 65536;
    unsigned short* w1t = wot + 65536;
    unsigned short* w2t = w1t + 65536;

    dim3 gemm_grid(128, 4);

    prep_w<<<dim3(8, 8, 6), 256, 0, stream>>>(Wq, Wk, Wv, Wo, W1, W2,
                                              wqt, wkt, wvt, wot, w1t, w2t);
    // 1. ln1 = LN(x) -> bf16
    ln_kernel<<<B_ * N_, 256, 0, stream>>>(x, g1, be1, lnb);
    // 2. q, k, V^T in ONE launch (z==2 writes transposed V directly)
    gemm_qkv<<<dim3(128, 4, 3), 256, 0, stream>>>(lnb, wqt, qb, wkt, kb, wvt, vtb);
    // 3. attention (bf16 out into lnb); 512 blocks, 2/CU
    attn_mfma<<<B_ * (N_ / QT) * 2, 256, 0, stream>>>(qb, kb, vtb, infl,
                                                      iw1, ib1, iw2, ib2, lnb);
    // 4. h = attn @ Wo + bo + x (fp32)
    gemm_mfma<<<gemm_grid, 256, 0, stream>>>(lnb, wot, bo, x, hb, 0, 0);
    // 5. ln2 = LN(h) -> bf16
    ln_kernel<<<B_ * N_, 256, 0, stream>>>(hb, g2, be2, lnb);
    // 6. t = relu(ln2 @ W1 + b1) -> bf16 (reuse qb)
    gemm_mfma<<<gemm_grid, 256, 0, stream>>>(lnb, w1t, b1, nullptr, qb, 1, 1);
    // 7. out = t @ W2 + b2 + h (fp32)
    gemm_mfma<<<gemm_grid, 256, 0, stream>>>(qb, w2t, b2, hb, (float*)d_out, 0, 0);
}

// Round 12
// 133.637 us; speedup vs baseline: 1.4240x; 1.0255x over previous
//
#include <hip/hip_runtime.h>
#include <hip/hip_bf16.h>

#define B_  4
#define N_  2048
#define E_  256
#define H_  8
#define D_  32
#define QT  32   // q-rows per block
#define KC  64   // keys per chunk
#define HPB 4    // heads per block
#define VTP 72   // V^T row stride (ushorts): 144B
#define PP  72   // P row stride (ushorts)
#define IFPF 68  // infl row stride (floats): 272B
#define LOG2E 1.4426950408889634f

typedef __attribute__((ext_vector_type(8))) short bfx8;
typedef __attribute__((ext_vector_type(4))) float fx4;

__device__ __forceinline__ unsigned short f2bf(float f) {
    unsigned int u = __float_as_uint(f);
    u += 0x7fffu + ((u >> 16) & 1u);   // round-to-nearest-even
    return (unsigned short)(u >> 16);
}

// pack two f32 -> two bf16 (RNE) in one VALU op
__device__ __forceinline__ unsigned int cvt_pk_bf16(float lo, float hi) {
    unsigned int r;
    asm("v_cvt_pk_bf16_f32 %0, %1, %2" : "=v"(r) : "v"(lo), "v"(hi));
    return r;
}

// ---------- prep: Wt[n][k] = bf16(W[k][n]) for 6 weight matrices ----------
__global__ __launch_bounds__(256) void prep_w(
    const float* Wa, const float* Wb, const float* Wc,
    const float* Wd, const float* We, const float* Wf,
    unsigned short* Oa, unsigned short* Ob, unsigned short* Oc,
    unsigned short* Od, unsigned short* Oe, unsigned short* Of)
{
    int z = blockIdx.z;
    const float* src = z == 0 ? Wa : z == 1 ? Wb : z == 2 ? Wc
                     : z == 3 ? Wd : z == 4 ? We : Wf;
    unsigned short* dst = z == 0 ? Oa : z == 1 ? Ob : z == 2 ? Oc
                        : z == 3 ? Od : z == 4 ? Oe : Of;
    __shared__ float t[32][33];
    int n0 = blockIdx.x * 32, k0 = blockIdx.y * 32;
    int tx = threadIdx.x & 31, ty = threadIdx.x >> 5;
#pragma unroll
    for (int i = 0; i < 4; i++)
        t[ty + i * 8][tx] = src[(k0 + ty + i * 8) * E_ + n0 + tx];
    __syncthreads();
#pragma unroll
    for (int i = 0; i < 4; i++)
        dst[(n0 + ty + i * 8) * E_ + k0 + tx] = f2bf(t[tx][ty + i * 8]);
}

// ---------- LayerNorm: one block (256 thr) per row; bf16 out ----------
__global__ __launch_bounds__(256) void ln_kernel(const float* __restrict__ x,
                                                 const float* __restrict__ g,
                                                 const float* __restrict__ be,
                                                 unsigned short* __restrict__ out)
{
    long row = blockIdx.x;
    int t = threadIdx.x;
    float v = x[row * E_ + t];
    float s = v, s2 = v * v;
#pragma unroll
    for (int off = 32; off; off >>= 1) {
        s  += __shfl_xor(s,  off, 64);
        s2 += __shfl_xor(s2, off, 64);
    }
    __shared__ float rs[4], rs2[4];
    int w = t >> 6;
    if ((t & 63) == 0) { rs[w] = s; rs2[w] = s2; }
    __syncthreads();
    s  = rs[0] + rs[1] + rs[2] + rs[3];
    s2 = rs2[0] + rs2[1] + rs2[2] + rs2[3];
    float mu  = s * (1.0f / E_);
    float var = s2 * (1.0f / E_) - mu * mu;
    float rstd = rsqrtf(var + 1e-5f);
    out[row * E_ + t] = f2bf((v - mu) * rstd * g[t] + be[t]);
}

// ---------- bf16 MFMA GEMM core (64x64 tile, K=256 strip in LDS) ----------
// C[m][n] = sum_k A[m][k] * Wt[n][k]; C stride = ldC.
__device__ __forceinline__ void gemm_core(
    const unsigned short* __restrict__ A,
    const unsigned short* __restrict__ Wt,
    const float* __restrict__ bias,
    const float* __restrict__ resid,
    void* __restrict__ Cv, int relu, int obf, int m0, int n0, int ldC)
{
    __shared__ unsigned short As[64 * 264];
    __shared__ unsigned short Bs[64 * 264];
    int tid = threadIdx.x;

    {   // stage both 64x256 strips (contiguous rows), coalesced 16B/lane
        const unsigned short* Ab = A  + (long)m0 * E_;
        const unsigned short* Bb = Wt + (long)n0 * E_;
        bfx8 va[8], vb[8];
#pragma unroll
        for (int i = 0; i < 8; i++) va[i] = *(const bfx8*)&Ab[(i * 256 + tid) * 8];
#pragma unroll
        for (int i = 0; i < 8; i++) vb[i] = *(const bfx8*)&Bb[(i * 256 + tid) * 8];
#pragma unroll
        for (int i = 0; i < 8; i++) {
            int fo = i * 256 + tid;
            int row = fo >> 5, c8 = fo & 31;
            *(bfx8*)&As[row * 264 + c8 * 8] = va[i];
            *(bfx8*)&Bs[row * 264 + c8 * 8] = vb[i];
        }
    }
    __syncthreads();

    int lane = tid & 63, w = tid >> 6;
    int c = lane & 15, g = lane >> 4;
    int wm = (w >> 1) * 32, wn = (w & 1) * 32;
    fx4 acc[2][2] = {};

#pragma unroll
    for (int ks = 0; ks < 8; ks++) {
        bfx8 a0 = *(const bfx8*)&As[(wm + c)      * 264 + ks * 32 + g * 8];
        bfx8 a1 = *(const bfx8*)&As[(wm + 16 + c) * 264 + ks * 32 + g * 8];
        bfx8 b0 = *(const bfx8*)&Bs[(wn + c)      * 264 + ks * 32 + g * 8];
        bfx8 b1 = *(const bfx8*)&Bs[(wn + 16 + c) * 264 + ks * 32 + g * 8];
        acc[0][0] = __builtin_amdgcn_mfma_f32_16x16x32_bf16(a0, b0, acc[0][0], 0, 0, 0);
        acc[0][1] = __builtin_amdgcn_mfma_f32_16x16x32_bf16(a0, b1, acc[0][1], 0, 0, 0);
        acc[1][0] = __builtin_amdgcn_mfma_f32_16x16x32_bf16(a1, b0, acc[1][0], 0, 0, 0);
        acc[1][1] = __builtin_amdgcn_mfma_f32_16x16x32_bf16(a1, b1, acc[1][1], 0, 0, 0);
    }

#pragma unroll
    for (int fm = 0; fm < 2; fm++)
#pragma unroll
        for (int r = 0; r < 4; r++) {
            int m = m0 + wm + fm * 16 + g * 4 + r;
#pragma unroll
            for (int fn = 0; fn < 2; fn++) {
                int n = n0 + wn + fn * 16 + c;
                float o = acc[fm][fn][r];
                if (bias)  o += bias[n];
                if (relu)  o = fmaxf(o, 0.f);
                if (resid) o += resid[(long)m * ldC + n];
                if (obf) ((unsigned short*)Cv)[(long)m * ldC + n] = f2bf(o);
                else     ((float*)Cv)[(long)m * ldC + n] = o;
            }
        }
}

__global__ __launch_bounds__(256, 2) void gemm_mfma(
    const unsigned short* __restrict__ A,
    const unsigned short* __restrict__ Wt,
    const float* __restrict__ bias,
    const float* __restrict__ resid,
    void* __restrict__ Cv, int relu, int obf)
{
    gemm_core(A, Wt, bias, resid, Cv, relu, obf,
              blockIdx.x * 64, blockIdx.y * 64, E_);
}

// merged QKV. z==2 computes V^T: Vt[ch][tok] = sum_k Wvt[ch][k]*X[tok][k]
// (roles of A/W swapped; channel-major output, ldC = 8192).
__global__ __launch_bounds__(256, 2) void gemm_qkv(
    const unsigned short* __restrict__ A,
    const unsigned short* __restrict__ Wq, unsigned short* __restrict__ qo,
    const unsigned short* __restrict__ Wk, unsigned short* __restrict__ ko,
    const unsigned short* __restrict__ Wv, unsigned short* __restrict__ vto)
{
    int z = blockIdx.z;
    if (z == 2) {
        gemm_core(Wv, A, nullptr, nullptr, vto, 0, 1,
                  blockIdx.y * 64, blockIdx.x * 64, B_ * N_);
    } else {
        const unsigned short* Wt = z == 0 ? Wq : Wk;
        unsigned short*       Cv = z == 0 ? qo : ko;
        gemm_core(A, Wt, nullptr, nullptr, Cv, 0, 1,
                  blockIdx.x * 64, blockIdx.y * 64, E_);
    }
}

// ---------- MFMA flash attention: QT=32, 4 heads/block, dbuf infl ------------
// R11 structure + (1) influence pre-transformed ONCE per block by the stager:
//   a = fr*iw1*log2e + (ib1*log2e - M2),  b = fr*iw2 + ib2
//   softmax per score: s = fma(st, scale2, a); p = exp2(s); pr = p*b
// (2) P pack via v_cvt_pk_bf16_f32 (1 op/pair). 1 barrier/body.
__global__ __launch_bounds__(256, 2) void attn_mfma(
    const unsigned short* __restrict__ q,
    const unsigned short* __restrict__ k,
    const unsigned short* __restrict__ vt,   // [E_][B_*N_] channel-major
    const float* __restrict__ infl,
    const float* __restrict__ iw1p, const float* __restrict__ ib1p,
    const float* __restrict__ iw2p, const float* __restrict__ ib2p,
    unsigned short* __restrict__ out)
{
    const int bx  = blockIdx.x;                 // 512 blocks
    const int xcd = bx & 7;
    const int b   = xcd >> 1;                   // batch
    const int hg  = (xcd & 1) * HPB;            // head-group base
    const int q0  = (bx >> 3) * QT;
    const int tid = threadIdx.x;
    const int h    = tid >> 6;                  // wave id 0..3
    const int head = hg + h;
    const int lane = tid & 63;
    const int c = lane & 15, g = lane >> 4, g4 = g * 4;

    const float iw1e = iw1p[0] * LOG2E, ib1e = ib1p[0] * LOG2E;
    const float iw2 = iw2p[0], ib2 = ib2p[0];
    const float scale2 = 0.17677669529663687f * LOG2E;  // log2e/sqrt(32)
    const float cadd = ib1e - 16.0f * LOG2E;            // ib1*log2e - M2

    __shared__ unsigned short vt_lds[HPB][D_][VTP];     // 18432B wave-private
    __shared__ unsigned short p_lds[HPB][QT][PP];       // 18432B wave-private
    __shared__ float ab_lds[2][2][QT][IFPF];            // 34816B block dbuf (a,b)

    // Q fragments (2 q-subtiles)
    bfx8 qf0 = *(const bfx8*)&q[((long)(b * N_ + q0 +      c)) * E_ + head * D_ + g * 8];
    bfx8 qf1 = *(const bfx8*)&q[((long)(b * N_ + q0 + 16 + c)) * E_ + head * D_ + g * 8];

    const unsigned short* kbase = &k[((long)(b * N_) + c) * E_ + head * D_ + g * 8];
    // V^T staging coords: row = (lane>>3)+8i (d-channel), keys = (lane&7)*8
    const long MT = (long)B_ * N_;   // 8192
    const int vrow = lane >> 3, vcol = (lane & 7) * 8;
    const unsigned short* vtg = &vt[((long)(head * D_ + vrow)) * MT + b * N_ + vcol];

    // cooperative infl staging: 256 thr = 32 rows x 8 thr; 8 floats each
    const int irow = tid >> 3, icol = (tid & 7) * 8;
    const float* ibase = &infl[((long)(b * N_ + q0 + irow)) * N_ + icol];

    fx4 o00 = {0,0,0,0}, o01 = {0,0,0,0}, o10 = {0,0,0,0}, o11 = {0,0,0,0};
    float l0 = 0.f, l1 = 0.f;
    const fx4 zero = {0,0,0,0};
    fx4 st[2][4];   // [qs][kt], compile-time indices only

    // helper: transform+write one 8-float strip into ab_lds[buf]
    auto stage_ab = [&](int buf, float4 x0, float4 x1) {
        float4 a0, a1, b0, b1;
        a0.x = fmaf(x0.x, iw1e, cadd); b0.x = fmaf(x0.x, iw2, ib2);
        a0.y = fmaf(x0.y, iw1e, cadd); b0.y = fmaf(x0.y, iw2, ib2);
        a0.z = fmaf(x0.z, iw1e, cadd); b0.z = fmaf(x0.z, iw2, ib2);
        a0.w = fmaf(x0.w, iw1e, cadd); b0.w = fmaf(x0.w, iw2, ib2);
        a1.x = fmaf(x1.x, iw1e, cadd); b1.x = fmaf(x1.x, iw2, ib2);
        a1.y = fmaf(x1.y, iw1e, cadd); b1.y = fmaf(x1.y, iw2, ib2);
        a1.z = fmaf(x1.z, iw1e, cadd); b1.z = fmaf(x1.z, iw2, ib2);
        a1.w = fmaf(x1.w, iw1e, cadd); b1.w = fmaf(x1.w, iw2, ib2);
        *(float4*)&ab_lds[buf][0][irow][icol]     = a0;
        *(float4*)&ab_lds[buf][0][irow][icol + 4] = a1;
        *(float4*)&ab_lds[buf][1][irow][icol]     = b0;
        *(float4*)&ab_lds[buf][1][irow][icol + 4] = b1;
    };

    // ---------------- prologue: chunk 0 ----------------
    float4 i00 = *(const float4*)&ibase[0];
    float4 i01 = *(const float4*)&ibase[4];
    float4 fA0 = *(const float4*)&ibase[KC];
    float4 fA1 = *(const float4*)&ibase[KC + 4];
    bfx8 nk0 = *(const bfx8*)(kbase +  0L * E_);
    bfx8 nk1 = *(const bfx8*)(kbase + 16L * E_);
    bfx8 nk2 = *(const bfx8*)(kbase + 32L * E_);
    bfx8 nk3 = *(const bfx8*)(kbase + 48L * E_);
    bfx8 nv0 = *(const bfx8*)(vtg +  0L * MT);
    bfx8 nv1 = *(const bfx8*)(vtg +  8L * MT);
    bfx8 nv2 = *(const bfx8*)(vtg + 16L * MT);
    bfx8 nv3 = *(const bfx8*)(vtg + 24L * MT);
    stage_ab(0, i00, i01);
    __syncthreads();
    // QK(0)
    __builtin_amdgcn_s_setprio(1);
    st[0][0] = __builtin_amdgcn_mfma_f32_16x16x32_bf16(nk0, qf0, zero, 0, 0, 0);
    st[1][0] = __builtin_amdgcn_mfma_f32_16x16x32_bf16(nk0, qf1, zero, 0, 0, 0);
    st[0][1] = __builtin_amdgcn_mfma_f32_16x16x32_bf16(nk1, qf0, zero, 0, 0, 0);
    st[1][1] = __builtin_amdgcn_mfma_f32_16x16x32_bf16(nk1, qf1, zero, 0, 0, 0);
    st[0][2] = __builtin_amdgcn_mfma_f32_16x16x32_bf16(nk2, qf0, zero, 0, 0, 0);
    st[1][2] = __builtin_amdgcn_mfma_f32_16x16x32_bf16(nk2, qf1, zero, 0, 0, 0);
    st[0][3] = __builtin_amdgcn_mfma_f32_16x16x32_bf16(nk3, qf0, zero, 0, 0, 0);
    st[1][3] = __builtin_amdgcn_mfma_f32_16x16x32_bf16(nk3, qf1, zero, 0, 0, 0);
    __builtin_amdgcn_s_setprio(0);
    {   // V-stage(0): straight b128 copies, no VALU
        *(bfx8*)&vt_lds[h][vrow     ][vcol] = nv0;
        *(bfx8*)&vt_lds[h][vrow +  8][vcol] = nv1;
        *(bfx8*)&vt_lds[h][vrow + 16][vcol] = nv2;
        *(bfx8*)&vt_lds[h][vrow + 24][vcol] = nv3;
    }

    // ---------------- main loop ----------------
    for (int kk = 0; kk < N_; kk += KC) {
        const int cur = (kk >> 6) & 1, nxt = cur ^ 1;
        const int kn  = (kk +     KC) & (N_ - 1);
        const int kn2 = (kk + 2 * KC) & (N_ - 1);

        // issue next-chunk loads (V^T, K; infl 2 ahead)
        nv0 = *(const bfx8*)(vtg +  0L * MT + kn);
        nv1 = *(const bfx8*)(vtg +  8L * MT + kn);
        nv2 = *(const bfx8*)(vtg + 16L * MT + kn);
        nv3 = *(const bfx8*)(vtg + 24L * MT + kn);
        nk0 = *(const bfx8*)(kbase + (long)(kn +  0) * E_);
        nk1 = *(const bfx8*)(kbase + (long)(kn + 16) * E_);
        nk2 = *(const bfx8*)(kbase + (long)(kn + 32) * E_);
        nk3 = *(const bfx8*)(kbase + (long)(kn + 48) * E_);
        float4 fN0 = *(const float4*)&ibase[kn2];
        float4 fN1 = *(const float4*)&ibase[kn2 + 4];

        // transform+write infl(kk+1) into buf[nxt] from regs loaded LAST body
        stage_ab(nxt, fA0, fA1);

        // softmax(kk): st + a/b planes -> pr -> p_lds
#pragma unroll
        for (int qs = 0; qs < 2; qs++) {
#pragma unroll
            for (int t = 0; t < 4; t++) {
                float4 a4 = *(const float4*)&ab_lds[cur][0][qs * 16 + c][t * 16 + g4];
                float4 b4 = *(const float4*)&ab_lds[cur][1][qs * 16 + c][t * 16 + g4];
                float a[4] = {a4.x, a4.y, a4.z, a4.w};
                float bb[4] = {b4.x, b4.y, b4.z, b4.w};
                float pr[4];
#pragma unroll
                for (int r = 0; r < 4; r++) {
                    float s = fmaf(st[qs][t][r], scale2, a[r]);
                    float p = __builtin_amdgcn_exp2f(s);
                    if (qs == 0) l0 += p; else l1 += p;
                    pr[r] = p * bb[r];
                }
                unsigned int lo = cvt_pk_bf16(pr[0], pr[1]);
                unsigned int hi = cvt_pk_bf16(pr[2], pr[3]);
                *(uint2*)&p_lds[h][qs * 16 + c][t * 16 + g4] = make_uint2(lo, hi);
            }
        }

        // PV(kk)
        __builtin_amdgcn_s_setprio(1);
#pragma unroll
        for (int kh = 0; kh < 2; kh++) {
            bfx8 vf0 = *(const bfx8*)&vt_lds[h][c][g * 8 + kh * 32];
            bfx8 vf1 = *(const bfx8*)&vt_lds[h][16 + c][g * 8 + kh * 32];
            bfx8 pf0 = *(const bfx8*)&p_lds[h][c][g * 8 + kh * 32];
            bfx8 pf1 = *(const bfx8*)&p_lds[h][16 + c][g * 8 + kh * 32];
            o00 = __builtin_amdgcn_mfma_f32_16x16x32_bf16(pf0, vf0, o00, 0, 0, 0);
            o01 = __builtin_amdgcn_mfma_f32_16x16x32_bf16(pf0, vf1, o01, 0, 0, 0);
            o10 = __builtin_amdgcn_mfma_f32_16x16x32_bf16(pf1, vf0, o10, 0, 0, 0);
            o11 = __builtin_amdgcn_mfma_f32_16x16x32_bf16(pf1, vf1, o11, 0, 0, 0);
        }
        __builtin_amdgcn_s_setprio(0);

        __syncthreads();   // buf[cur] reads done; buf[nxt] writes visible

        if (kk != N_ - KC) {
            // QK(kk+1): K issued one body ago
            __builtin_amdgcn_s_setprio(1);
            st[0][0] = __builtin_amdgcn_mfma_f32_16x16x32_bf16(nk0, qf0, zero, 0, 0, 0);
            st[1][0] = __builtin_amdgcn_mfma_f32_16x16x32_bf16(nk0, qf1, zero, 0, 0, 0);
            st[0][1] = __builtin_amdgcn_mfma_f32_16x16x32_bf16(nk1, qf0, zero, 0, 0, 0);
            st[1][1] = __builtin_amdgcn_mfma_f32_16x16x32_bf16(nk1, qf1, zero, 0, 0, 0);
            st[0][2] = __builtin_amdgcn_mfma_f32_16x16x32_bf16(nk2, qf0, zero, 0, 0, 0);
            st[1][2] = __builtin_amdgcn_mfma_f32_16x16x32_bf16(nk2, qf1, zero, 0, 0, 0);
            st[0][3] = __builtin_amdgcn_mfma_f32_16x16x32_bf16(nk3, qf0, zero, 0, 0, 0);
            st[1][3] = __builtin_amdgcn_mfma_f32_16x16x32_bf16(nk3, qf1, zero, 0, 0, 0);
            __builtin_amdgcn_s_setprio(0);
            // V-stage(kk+1): b128 copies
            *(bfx8*)&vt_lds[h][vrow     ][vcol] = nv0;
            *(bfx8*)&vt_lds[h][vrow +  8][vcol] = nv1;
            *(bfx8*)&vt_lds[h][vrow + 16][vcol] = nv2;
            *(bfx8*)&vt_lds[h][vrow + 24][vcol] = nv3;
        }
        fA0 = fN0; fA1 = fN1;
    }

    // ---------------- epilogue ----------------
    float l0r = l0;
    l0r += __shfl_xor(l0r, 16); l0r += __shfl_xor(l0r, 32);
    float l1r = l1;
    l1r += __shfl_xor(l1r, 16); l1r += __shfl_xor(l1r, 32);
#pragma unroll
    for (int r = 0; r < 4; r++) {
        int src = (lane & 48) | (g4 + r);
        float inv0 = 1.0f / __shfl(l0r, src, 64);
        float inv1 = 1.0f / __shfl(l1r, src, 64);
        long row0 = ((long)(b * N_ + q0 +      g4 + r)) * E_ + head * D_;
        long row1 = ((long)(b * N_ + q0 + 16 + g4 + r)) * E_ + head * D_;
        out[row0 + c]      = f2bf(o00[r] * inv0);
        out[row0 + 16 + c] = f2bf(o01[r] * inv0);
        out[row1 + c]      = f2bf(o10[r] * inv1);
        out[row1 + 16 + c] = f2bf(o11[r] * inv1);
    }
}

// ------------------------------- launch ---------------------------------------
extern "C" void kernel_launch(void* const* d_in, const int* in_sizes, int n_in,
                              void* d_out, int out_size, void* d_ws, size_t ws_size,
                              hipStream_t stream)
{
    (void)in_sizes; (void)n_in; (void)out_size; (void)ws_size;
    const float* x    = (const float*)d_in[0];
    const float* infl = (const float*)d_in[1];
    const float* Wq   = (const float*)d_in[2];
    const float* Wk   = (const float*)d_in[3];
    const float* Wv   = (const float*)d_in[4];
    const float* Wo   = (const float*)d_in[5];
    const float* bo   = (const float*)d_in[6];
    const float* iw1  = (const float*)d_in[7];
    const float* ib1  = (const float*)d_in[8];
    const float* iw2  = (const float*)d_in[9];
    const float* ib2  = (const float*)d_in[10];
    const float* W1   = (const float*)d_in[11];
    const float* b1   = (const float*)d_in[12];
    const float* W2   = (const float*)d_in[13];
    const float* b2   = (const float*)d_in[14];
    const float* g1   = (const float*)d_in[15];
    const float* be1  = (const float*)d_in[16];
    const float* g2   = (const float*)d_in[17];
    const float* be2  = (const float*)d_in[18];

    char* base = (char*)d_ws;
    float*          hb  = (float*)base;                                   // 8 MB
    unsigned short* lnb = (unsigned short*)(base + (8  << 20));           // 4 MB
    unsigned short* qb  = (unsigned short*)(base + (12 << 20));           // 4 MB
    unsigned short* kb  = (unsigned short*)(base + (16 << 20));           // 4 MB
    unsigned short* vtb = (unsigned short*)(base + (20 << 20));           // 4 MB (V^T)
    unsigned short* wqt = (unsigned short*)(base + (24 << 20));           // 6x128KB
    unsigned short* wkt = wqt + 65536;
    unsigned short* wvt = wkt + 65536;
    unsigned short* wot = wvt + 65536;
    unsigned short* w1t = wot + 65536;
    unsigned short* w2t = w1t + 65536;

    dim3 gemm_grid(128, 4);

    prep_w<<<dim3(8, 8, 6), 256, 0, stream>>>(Wq, Wk, Wv, Wo, W1, W2,
                                              wqt, wkt, wvt, wot, w1t, w2t);
    // 1. ln1 = LN(x) -> bf16
    ln_kernel<<<B_ * N_, 256, 0, stream>>>(x, g1, be1, lnb);
    // 2. q, k, V^T in ONE launch (z==2 writes transposed V directly)
    gemm_qkv<<<dim3(128, 4, 3), 256, 0, stream>>>(lnb, wqt, qb, wkt, kb, wvt, vtb);
    // 3. attention (bf16 out into lnb); 512 blocks, 2/CU
    attn_mfma<<<B_ * (N_ / QT) * 2, 256, 0, stream>>>(qb, kb, vtb, infl,
                                                      iw1, ib1, iw2, ib2, lnb);
    // 4. h = attn @ Wo + bo + x (fp32)
    gemm_mfma<<<gemm_grid, 256, 0, stream>>>(lnb, wot, bo, x, hb, 0, 0);
    // 5. ln2 = LN(h) -> bf16
    ln_kernel<<<B_ * N_, 256, 0, stream>>>(hb, g2, be2, lnb);
    // 6. t = relu(ln2 @ W1 + b1) -> bf16 (reuse qb)
    gemm_mfma<<<gemm_grid, 256, 0, stream>>>(lnb, w1t, b1, nullptr, qb, 1, 1);
    // 7. out = t @ W2 + b2 + h (fp32)
    gemm_mfma<<<gemm_grid, 256, 0, stream>>>(qb, w2t, b2, hb, (float*)d_out, 0, 0);
}

// Round 13
// 124.604 us; speedup vs baseline: 1.5273x; 1.0725x over previous
//
#include <hip/hip_runtime.h>
#include <hip/hip_bf16.h>

#define B_  4
#define N_  2048
#define E_  256
#define H_  8
#define D_  32
#define QT  32   // q-rows per block
#define KC  64   // keys per chunk
#define HPB 4    // heads per block
#define VTP 72   // V^T row stride (ushorts): 144B
#define PP  72   // P row stride (ushorts)
#define IFP 68   // ab row stride (uints): 272B, 16B-aligned rows
#define LOG2E 1.4426950408889634f

typedef __attribute__((ext_vector_type(8))) short bfx8;
typedef __attribute__((ext_vector_type(4))) float fx4;

__device__ __forceinline__ unsigned short f2bf(float f) {
    unsigned int u = __float_as_uint(f);
    u += 0x7fffu + ((u >> 16) & 1u);   // round-to-nearest-even
    return (unsigned short)(u >> 16);
}

// pack two f32 -> two bf16 (RNE) in one VALU op: dst = bf16(lo) | bf16(hi)<<16
__device__ __forceinline__ unsigned int cvt_pk_bf16(float lo, float hi) {
    unsigned int r;
    asm("v_cvt_pk_bf16_f32 %0, %1, %2" : "=v"(r) : "v"(lo), "v"(hi));
    return r;
}

// ---------- prep: Wt[n][k] = bf16(W[k][n]) for 6 weight matrices ----------
__global__ __launch_bounds__(256) void prep_w(
    const float* Wa, const float* Wb, const float* Wc,
    const float* Wd, const float* We, const float* Wf,
    unsigned short* Oa, unsigned short* Ob, unsigned short* Oc,
    unsigned short* Od, unsigned short* Oe, unsigned short* Of)
{
    int z = blockIdx.z;
    const float* src = z == 0 ? Wa : z == 1 ? Wb : z == 2 ? Wc
                     : z == 3 ? Wd : z == 4 ? We : Wf;
    unsigned short* dst = z == 0 ? Oa : z == 1 ? Ob : z == 2 ? Oc
                        : z == 3 ? Od : z == 4 ? Oe : Of;
    __shared__ float t[32][33];
    int n0 = blockIdx.x * 32, k0 = blockIdx.y * 32;
    int tx = threadIdx.x & 31, ty = threadIdx.x >> 5;
#pragma unroll
    for (int i = 0; i < 4; i++)
        t[ty + i * 8][tx] = src[(k0 + ty + i * 8) * E_ + n0 + tx];
    __syncthreads();
#pragma unroll
    for (int i = 0; i < 4; i++)
        dst[(n0 + ty + i * 8) * E_ + k0 + tx] = f2bf(t[tx][ty + i * 8]);
}

// ---------- LayerNorm: ONE WAVE per row (pure shfl, no LDS); 4 rows/block ----
__global__ __launch_bounds__(256) void ln_kernel(const float* __restrict__ x,
                                                 const float* __restrict__ g,
                                                 const float* __restrict__ be,
                                                 unsigned short* __restrict__ out)
{
    const int w = threadIdx.x >> 6, lane = threadIdx.x & 63;
    const long row = (long)blockIdx.x * 4 + w;
    const float* xr = &x[row * E_];
    float4 v = *(const float4*)&xr[lane * 4];
    float s  = v.x + v.y + v.z + v.w;
    float s2 = v.x * v.x + v.y * v.y + v.z * v.z + v.w * v.w;
#pragma unroll
    for (int off = 32; off; off >>= 1) {
        s  += __shfl_xor(s,  off, 64);
        s2 += __shfl_xor(s2, off, 64);
    }
    float mu  = s * (1.0f / E_);
    float var = s2 * (1.0f / E_) - mu * mu;
    float rstd = rsqrtf(var + 1e-5f);
    float4 gg = *(const float4*)&g[lane * 4];
    float4 bb = *(const float4*)&be[lane * 4];
    float y0 = (v.x - mu) * rstd * gg.x + bb.x;
    float y1 = (v.y - mu) * rstd * gg.y + bb.y;
    float y2 = (v.z - mu) * rstd * gg.z + bb.z;
    float y3 = (v.w - mu) * rstd * gg.w + bb.w;
    uint2 o;
    o.x = cvt_pk_bf16(y0, y1);
    o.y = cvt_pk_bf16(y2, y3);
    *(uint2*)&out[row * E_ + lane * 4] = o;
}

// ---------- bf16 MFMA GEMM core (64x64 tile, K=256 strip in LDS) ----------
// C[m][n] = sum_k A[m][k] * Wt[n][k]; C stride = ldC.
__device__ __forceinline__ void gemm_core(
    const unsigned short* __restrict__ A,
    const unsigned short* __restrict__ Wt,
    const float* __restrict__ bias,
    const float* __restrict__ resid,
    void* __restrict__ Cv, int relu, int obf, int m0, int n0, int ldC)
{
    __shared__ unsigned short As[64 * 264];
    __shared__ unsigned short Bs[64 * 264];
    int tid = threadIdx.x;

    {   // stage both 64x256 strips (contiguous rows), coalesced 16B/lane
        const unsigned short* Ab = A  + (long)m0 * E_;
        const unsigned short* Bb = Wt + (long)n0 * E_;
        bfx8 va[8], vb[8];
#pragma unroll
        for (int i = 0; i < 8; i++) va[i] = *(const bfx8*)&Ab[(i * 256 + tid) * 8];
#pragma unroll
        for (int i = 0; i < 8; i++) vb[i] = *(const bfx8*)&Bb[(i * 256 + tid) * 8];
#pragma unroll
        for (int i = 0; i < 8; i++) {
            int fo = i * 256 + tid;
            int row = fo >> 5, c8 = fo & 31;
            *(bfx8*)&As[row * 264 + c8 * 8] = va[i];
            *(bfx8*)&Bs[row * 264 + c8 * 8] = vb[i];
        }
    }
    __syncthreads();

    int lane = tid & 63, w = tid >> 6;
    int c = lane & 15, g = lane >> 4;
    int wm = (w >> 1) * 32, wn = (w & 1) * 32;
    fx4 acc[2][2] = {};

#pragma unroll
    for (int ks = 0; ks < 8; ks++) {
        bfx8 a0 = *(const bfx8*)&As[(wm + c)      * 264 + ks * 32 + g * 8];
        bfx8 a1 = *(const bfx8*)&As[(wm + 16 + c) * 264 + ks * 32 + g * 8];
        bfx8 b0 = *(const bfx8*)&Bs[(wn + c)      * 264 + ks * 32 + g * 8];
        bfx8 b1 = *(const bfx8*)&Bs[(wn + 16 + c) * 264 + ks * 32 + g * 8];
        acc[0][0] = __builtin_amdgcn_mfma_f32_16x16x32_bf16(a0, b0, acc[0][0], 0, 0, 0);
        acc[0][1] = __builtin_amdgcn_mfma_f32_16x16x32_bf16(a0, b1, acc[0][1], 0, 0, 0);
        acc[1][0] = __builtin_amdgcn_mfma_f32_16x16x32_bf16(a1, b0, acc[1][0], 0, 0, 0);
        acc[1][1] = __builtin_amdgcn_mfma_f32_16x16x32_bf16(a1, b1, acc[1][1], 0, 0, 0);
    }

#pragma unroll
    for (int fm = 0; fm < 2; fm++)
#pragma unroll
        for (int r = 0; r < 4; r++) {
            int m = m0 + wm + fm * 16 + g * 4 + r;
#pragma unroll
            for (int fn = 0; fn < 2; fn++) {
                int n = n0 + wn + fn * 16 + c;
                float o = acc[fm][fn][r];
                if (bias)  o += bias[n];
                if (relu)  o = fmaxf(o, 0.f);
                if (resid) o += resid[(long)m * ldC + n];
                if (obf) ((unsigned short*)Cv)[(long)m * ldC + n] = f2bf(o);
                else     ((float*)Cv)[(long)m * ldC + n] = o;
            }
        }
}

__global__ __launch_bounds__(256, 2) void gemm_mfma(
    const unsigned short* __restrict__ A,
    const unsigned short* __restrict__ Wt,
    const float* __restrict__ bias,
    const float* __restrict__ resid,
    void* __restrict__ Cv, int relu, int obf)
{
    gemm_core(A, Wt, bias, resid, Cv, relu, obf,
              blockIdx.x * 64, blockIdx.y * 64, E_);
}

// merged QKV. z==2 computes V^T: Vt[ch][tok] = sum_k Wvt[ch][k]*X[tok][k]
// (roles of A/W swapped; channel-major output, ldC = 8192).
__global__ __launch_bounds__(256, 2) void gemm_qkv(
    const unsigned short* __restrict__ A,
    const unsigned short* __restrict__ Wq, unsigned short* __restrict__ qo,
    const unsigned short* __restrict__ Wk, unsigned short* __restrict__ ko,
    const unsigned short* __restrict__ Wv, unsigned short* __restrict__ vto)
{
    int z = blockIdx.z;
    if (z == 2) {
        gemm_core(Wv, A, nullptr, nullptr, vto, 0, 1,
                  blockIdx.y * 64, blockIdx.x * 64, B_ * N_);
    } else {
        const unsigned short* Wt = z == 0 ? Wq : Wk;
        unsigned short*       Cv = z == 0 ? qo : ko;
        gemm_core(A, Wt, nullptr, nullptr, Cv, 0, 1,
                  blockIdx.x * 64, blockIdx.y * 64, E_);
    }
}

// ---------- MFMA flash attention: QT=32, 4 heads/block, dbuf infl ------------
// ab plane: per key element ONE uint = bf16(a') | bf16(b)<<16 where
//   a' = fr*iw1*log2e + ib1*log2e   (no -M2 bias: the constant 2^cadd scales
//   numerator and denominator identically and cancels -> exact)
//   b  = fr*iw2 + ib2
// softmax: s = fma(st, scale2, a'); p = exp2(s); pr = p*b. uint4 reads (16B).
__global__ __launch_bounds__(256, 2) void attn_mfma(
    const unsigned short* __restrict__ q,
    const unsigned short* __restrict__ k,
    const unsigned short* __restrict__ vt,   // [E_][B_*N_] channel-major
    const float* __restrict__ infl,
    const float* __restrict__ iw1p, const float* __restrict__ ib1p,
    const float* __restrict__ iw2p, const float* __restrict__ ib2p,
    unsigned short* __restrict__ out)
{
    const int bx  = blockIdx.x;                 // 512 blocks
    const int xcd = bx & 7;
    const int b   = xcd >> 1;                   // batch
    const int hg  = (xcd & 1) * HPB;            // head-group base
    const int q0  = (bx >> 3) * QT;
    const int tid = threadIdx.x;
    const int h    = tid >> 6;                  // wave id 0..3
    const int head = hg + h;
    const int lane = tid & 63;
    const int c = lane & 15, g = lane >> 4, g4 = g * 4;

    const float iw1e = iw1p[0] * LOG2E, ib1e = ib1p[0] * LOG2E;
    const float iw2 = iw2p[0], ib2 = ib2p[0];
    const float scale2 = 0.17677669529663687f * LOG2E;  // log2e/sqrt(32)

    __shared__ unsigned short vt_lds[HPB][D_][VTP];     // 18432B wave-private
    __shared__ unsigned short p_lds[HPB][QT][PP];       // 18432B wave-private
    __shared__ unsigned int ab_lds[2][QT][IFP];         // 17408B block dbuf

    // Q fragments (2 q-subtiles)
    bfx8 qf0 = *(const bfx8*)&q[((long)(b * N_ + q0 +      c)) * E_ + head * D_ + g * 8];
    bfx8 qf1 = *(const bfx8*)&q[((long)(b * N_ + q0 + 16 + c)) * E_ + head * D_ + g * 8];

    const unsigned short* kbase = &k[((long)(b * N_) + c) * E_ + head * D_ + g * 8];
    // V^T staging coords: row = (lane>>3)+8i (d-channel), keys = (lane&7)*8
    const long MT = (long)B_ * N_;   // 8192
    const int vrow = lane >> 3, vcol = (lane & 7) * 8;
    const unsigned short* vtg = &vt[((long)(head * D_ + vrow)) * MT + b * N_ + vcol];

    // cooperative infl staging: 256 thr = 32 rows x 8 thr; 8 floats each
    const int irow = tid >> 3, icol = (tid & 7) * 8;
    const float* ibase = &infl[((long)(b * N_ + q0 + irow)) * N_ + icol];

    fx4 o00 = {0,0,0,0}, o01 = {0,0,0,0}, o10 = {0,0,0,0}, o11 = {0,0,0,0};
    float l0 = 0.f, l1 = 0.f;
    const fx4 zero = {0,0,0,0};
    fx4 st[2][4];   // [qs][kt], compile-time indices only

    // transform+pack one 8-float strip into ab_lds[buf] (bf16 a'|b pairs)
    auto stage_ab = [&](int buf, float4 x0, float4 x1) {
        float xs[8] = {x0.x, x0.y, x0.z, x0.w, x1.x, x1.y, x1.z, x1.w};
        unsigned int u[8];
#pragma unroll
        for (int i = 0; i < 8; i++) {
            float a = fmaf(xs[i], iw1e, ib1e);
            float bb = fmaf(xs[i], iw2, ib2);
            u[i] = cvt_pk_bf16(a, bb);
        }
        uint4 lo = {u[0], u[1], u[2], u[3]};
        uint4 hi = {u[4], u[5], u[6], u[7]};
        *(uint4*)&ab_lds[buf][irow][icol]     = lo;
        *(uint4*)&ab_lds[buf][irow][icol + 4] = hi;
    };

    // ---------------- prologue: chunk 0 ----------------
    float4 i00 = *(const float4*)&ibase[0];
    float4 i01 = *(const float4*)&ibase[4];
    float4 fA0 = *(const float4*)&ibase[KC];
    float4 fA1 = *(const float4*)&ibase[KC + 4];
    bfx8 nk0 = *(const bfx8*)(kbase +  0L * E_);
    bfx8 nk1 = *(const bfx8*)(kbase + 16L * E_);
    bfx8 nk2 = *(const bfx8*)(kbase + 32L * E_);
    bfx8 nk3 = *(const bfx8*)(kbase + 48L * E_);
    bfx8 nv0 = *(const bfx8*)(vtg +  0L * MT);
    bfx8 nv1 = *(const bfx8*)(vtg +  8L * MT);
    bfx8 nv2 = *(const bfx8*)(vtg + 16L * MT);
    bfx8 nv3 = *(const bfx8*)(vtg + 24L * MT);
    stage_ab(0, i00, i01);
    __syncthreads();
    // QK(0)
    __builtin_amdgcn_s_setprio(1);
    st[0][0] = __builtin_amdgcn_mfma_f32_16x16x32_bf16(nk0, qf0, zero, 0, 0, 0);
    st[1][0] = __builtin_amdgcn_mfma_f32_16x16x32_bf16(nk0, qf1, zero, 0, 0, 0);
    st[0][1] = __builtin_amdgcn_mfma_f32_16x16x32_bf16(nk1, qf0, zero, 0, 0, 0);
    st[1][1] = __builtin_amdgcn_mfma_f32_16x16x32_bf16(nk1, qf1, zero, 0, 0, 0);
    st[0][2] = __builtin_amdgcn_mfma_f32_16x16x32_bf16(nk2, qf0, zero, 0, 0, 0);
    st[1][2] = __builtin_amdgcn_mfma_f32_16x16x32_bf16(nk2, qf1, zero, 0, 0, 0);
    st[0][3] = __builtin_amdgcn_mfma_f32_16x16x32_bf16(nk3, qf0, zero, 0, 0, 0);
    st[1][3] = __builtin_amdgcn_mfma_f32_16x16x32_bf16(nk3, qf1, zero, 0, 0, 0);
    __builtin_amdgcn_s_setprio(0);
    {   // V-stage(0): straight b128 copies, no VALU
        *(bfx8*)&vt_lds[h][vrow     ][vcol] = nv0;
        *(bfx8*)&vt_lds[h][vrow +  8][vcol] = nv1;
        *(bfx8*)&vt_lds[h][vrow + 16][vcol] = nv2;
        *(bfx8*)&vt_lds[h][vrow + 24][vcol] = nv3;
    }

    // ---------------- main loop ----------------
    for (int kk = 0; kk < N_; kk += KC) {
        const int cur = (kk >> 6) & 1, nxt = cur ^ 1;
        const int kn  = (kk +     KC) & (N_ - 1);
        const int kn2 = (kk + 2 * KC) & (N_ - 1);

        // issue next-chunk loads (V^T, K; infl 2 ahead)
        nv0 = *(const bfx8*)(vtg +  0L * MT + kn);
        nv1 = *(const bfx8*)(vtg +  8L * MT + kn);
        nv2 = *(const bfx8*)(vtg + 16L * MT + kn);
        nv3 = *(const bfx8*)(vtg + 24L * MT + kn);
        nk0 = *(const bfx8*)(kbase + (long)(kn +  0) * E_);
        nk1 = *(const bfx8*)(kbase + (long)(kn + 16) * E_);
        nk2 = *(const bfx8*)(kbase + (long)(kn + 32) * E_);
        nk3 = *(const bfx8*)(kbase + (long)(kn + 48) * E_);
        float4 fN0 = *(const float4*)&ibase[kn2];
        float4 fN1 = *(const float4*)&ibase[kn2 + 4];

        // transform+pack infl(kk+1) into buf[nxt] from regs loaded LAST body
        stage_ab(nxt, fA0, fA1);

        // softmax(kk): st + packed ab plane -> pr -> p_lds
#pragma unroll
        for (int qs = 0; qs < 2; qs++) {
#pragma unroll
            for (int t = 0; t < 4; t++) {
                uint4 u4 = *(const uint4*)&ab_lds[cur][qs * 16 + c][t * 16 + g4];
                unsigned int uu[4] = {u4.x, u4.y, u4.z, u4.w};
                float pr[4];
#pragma unroll
                for (int r = 0; r < 4; r++) {
                    float a  = __uint_as_float(uu[r] << 16);
                    float bb = __uint_as_float(uu[r] & 0xffff0000u);
                    float s = fmaf(st[qs][t][r], scale2, a);
                    float p = __builtin_amdgcn_exp2f(s);
                    if (qs == 0) l0 += p; else l1 += p;
                    pr[r] = p * bb;
                }
                unsigned int lo = cvt_pk_bf16(pr[0], pr[1]);
                unsigned int hi = cvt_pk_bf16(pr[2], pr[3]);
                *(uint2*)&p_lds[h][qs * 16 + c][t * 16 + g4] = make_uint2(lo, hi);
            }
        }

        // PV(kk)
        __builtin_amdgcn_s_setprio(1);
#pragma unroll
        for (int kh = 0; kh < 2; kh++) {
            bfx8 vf0 = *(const bfx8*)&vt_lds[h][c][g * 8 + kh * 32];
            bfx8 vf1 = *(const bfx8*)&vt_lds[h][16 + c][g * 8 + kh * 32];
            bfx8 pf0 = *(const bfx8*)&p_lds[h][c][g * 8 + kh * 32];
            bfx8 pf1 = *(const bfx8*)&p_lds[h][16 + c][g * 8 + kh * 32];
            o00 = __builtin_amdgcn_mfma_f32_16x16x32_bf16(pf0, vf0, o00, 0, 0, 0);
            o01 = __builtin_amdgcn_mfma_f32_16x16x32_bf16(pf0, vf1, o01, 0, 0, 0);
            o10 = __builtin_amdgcn_mfma_f32_16x16x32_bf16(pf1, vf0, o10, 0, 0, 0);
            o11 = __builtin_amdgcn_mfma_f32_16x16x32_bf16(pf1, vf1, o11, 0, 0, 0);
        }
        __builtin_amdgcn_s_setprio(0);

        __syncthreads();   // buf[cur] reads done; buf[nxt] writes visible

        if (kk != N_ - KC) {
            // QK(kk+1): K issued one body ago
            __builtin_amdgcn_s_setprio(1);
            st[0][0] = __builtin_amdgcn_mfma_f32_16x16x32_bf16(nk0, qf0, zero, 0, 0, 0);
            st[1][0] = __builtin_amdgcn_mfma_f32_16x16x32_bf16(nk0, qf1, zero, 0, 0, 0);
            st[0][1] = __builtin_amdgcn_mfma_f32_16x16x32_bf16(nk1, qf0, zero, 0, 0, 0);
            st[1][1] = __builtin_amdgcn_mfma_f32_16x16x32_bf16(nk1, qf1, zero, 0, 0, 0);
            st[0][2] = __builtin_amdgcn_mfma_f32_16x16x32_bf16(nk2, qf0, zero, 0, 0, 0);
            st[1][2] = __builtin_amdgcn_mfma_f32_16x16x32_bf16(nk2, qf1, zero, 0, 0, 0);
            st[0][3] = __builtin_amdgcn_mfma_f32_16x16x32_bf16(nk3, qf0, zero, 0, 0, 0);
            st[1][3] = __builtin_amdgcn_mfma_f32_16x16x32_bf16(nk3, qf1, zero, 0, 0, 0);
            __builtin_amdgcn_s_setprio(0);
            // V-stage(kk+1): b128 copies
            *(bfx8*)&vt_lds[h][vrow     ][vcol] = nv0;
            *(bfx8*)&vt_lds[h][vrow +  8][vcol] = nv1;
            *(bfx8*)&vt_lds[h][vrow + 16][vcol] = nv2;
            *(bfx8*)&vt_lds[h][vrow + 24][vcol] = nv3;
        }
        fA0 = fN0; fA1 = fN1;
    }

    // ---------------- epilogue ----------------
    float l0r = l0;
    l0r += __shfl_xor(l0r, 16); l0r += __shfl_xor(l0r, 32);
    float l1r = l1;
    l1r += __shfl_xor(l1r, 16); l1r += __shfl_xor(l1r, 32);
#pragma unroll
    for (int r = 0; r < 4; r++) {
        int src = (lane & 48) | (g4 + r);
        float inv0 = 1.0f / __shfl(l0r, src, 64);
        float inv1 = 1.0f / __shfl(l1r, src, 64);
        long row0 = ((long)(b * N_ + q0 +      g4 + r)) * E_ + head * D_;
        long row1 = ((long)(b * N_ + q0 + 16 + g4 + r)) * E_ + head * D_;
        out[row0 + c]      = f2bf(o00[r] * inv0);
        out[row0 + 16 + c] = f2bf(o01[r] * inv0);
        out[row1 + c]      = f2bf(o10[r] * inv1);
        out[row1 + 16 + c] = f2bf(o11[r] * inv1);
    }
}

// ------------------------------- launch ---------------------------------------
extern "C" void kernel_launch(void* const* d_in, const int* in_sizes, int n_in,
                              void* d_out, int out_size, void* d_ws, size_t ws_size,
                              hipStream_t stream)
{
    (void)in_sizes; (void)n_in; (void)out_size; (void)ws_size;
    const float* x    = (const float*)d_in[0];
    const float* infl = (const float*)d_in[1];
    const float* Wq   = (const float*)d_in[2];
    const float* Wk   = (const float*)d_in[3];
    const float* Wv   = (const float*)d_in[4];
    const float* Wo   = (const float*)d_in[5];
    const float* bo   = (const float*)d_in[6];
    const float* iw1  = (const float*)d_in[7];
    const float* ib1  = (const float*)d_in[8];
    const float* iw2  = (const float*)d_in[9];
    const float* ib2  = (const float*)d_in[10];
    const float* W1   = (const float*)d_in[11];
    const float* b1   = (const float*)d_in[12];
    const float* W2   = (const float*)d_in[13];
    const float* b2   = (const float*)d_in[14];
    const float* g1   = (const float*)d_in[15];
    const float* be1  = (const float*)d_in[16];
    const float* g2   = (const float*)d_in[17];
    const float* be2  = (const float*)d_in[18];

    char* base = (char*)d_ws;
    float*          hb  = (float*)base;                                   // 8 MB
    unsigned short* lnb = (unsigned short*)(base + (8  << 20));           // 4 MB
    unsigned short* qb  = (unsigned short*)(base + (12 << 20));           // 4 MB
    unsigned short* kb  = (unsigned short*)(base + (16 << 20));           // 4 MB
    unsigned short* vtb = (unsigned short*)(base + (20 << 20));           // 4 MB (V^T)
    unsigned short* wqt = (unsigned short*)(base + (24 << 20));           // 6x128KB
    unsigned short* wkt = wqt + 65536;
    unsigned short* wvt = wkt + 65536;
    unsigned short* wot = wvt + 65536;
    unsigned short* w1t = wot + 65536;
    unsigned short* w2t = w1t + 65536;

    dim3 gemm_grid(128, 4);

    prep_w<<<dim3(8, 8, 6), 256, 0, stream>>>(Wq, Wk, Wv, Wo, W1, W2,
                                              wqt, wkt, wvt, wot, w1t, w2t);
    // 1. ln1 = LN(x) -> bf16 (1 wave/row, 4 rows/block)
    ln_kernel<<<B_ * N_ / 4, 256, 0, stream>>>(x, g1, be1, lnb);
    // 2. q, k, V^T in ONE launch (z==2 writes transposed V directly)
    gemm_qkv<<<dim3(128, 4, 3), 256, 0, stream>>>(lnb, wqt, qb, wkt, kb, wvt, vtb);
    // 3. attention (bf16 out into lnb); 512 blocks, 2/CU
    attn_mfma<<<B_ * (N_ / QT) * 2, 256, 0, stream>>>(qb, kb, vtb, infl,
                                                      iw1, ib1, iw2, ib2, lnb);
    // 4. h = attn @ Wo + bo + x (fp32)
    gemm_mfma<<<gemm_grid, 256, 0, stream>>>(lnb, wot, bo, x, hb, 0, 0);
    // 5. ln2 = LN(h) -> bf16
    ln_kernel<<<B_ * N_ / 4, 256, 0, stream>>>(hb, g2, be2, lnb);
    // 6. t = relu(ln2 @ W1 + b1) -> bf16 (reuse qb)
    gemm_mfma<<<gemm_grid, 256, 0, stream>>>(lnb, w1t, b1, nullptr, qb, 1, 1);
    // 7. out = t @ W2 + b2 + h (fp32)
    gemm_mfma<<<gemm_grid, 256, 0, stream>>>(qb, w2t, b2, hb, (float*)d_out, 0, 0);
}